// Round 1
// baseline (90.779 us; speedup 1.0000x reference)
//
#include <hip/hip_runtime.h>

#define L_SEQ   512
#define NHEADS_ 8
#define HEADDIM_ 128
#define QKD     16
#define DINNER  1024
#define EPS_F   1e-3f
#define STD_F   0.0078125f   // 1/sqrt(2*512*16) = 1/128

typedef __attribute__((ext_vector_type(8))) short  short8;
typedef __attribute__((ext_vector_type(4))) float  floatx4;

// cos(2*pi*rev): v_cos_f32 takes revolutions; reduce to [0,1) first.
__device__ __forceinline__ float cosrev(float rev) {
    float r = rev - floorf(rev);
    return __builtin_amdgcn_cosf(r);
}

// float -> bf16 bits, round-to-nearest-even (inputs are finite, no NaN path needed)
__device__ __forceinline__ short f2bf(float x) {
    union { float f; unsigned int u; } v;
    v.f = x;
    unsigned int r = v.u + 0x7fffu + ((v.u >> 16) & 1u);
    return (short)(r >> 16);
}

// Stage 1: VT[bn][h][l] (bf16) = v[b, l, n*128+h]   -- 64x64 LDS tile transpose
__global__ __launch_bounds__(256) void vtrans_kernel(const float* __restrict__ v,
                                                     short* __restrict__ vt) {
    const int l0 = blockIdx.x * 64;
    const int h0 = blockIdx.y * 64;
    const int bn = blockIdx.z;
    const int b = bn >> 3, n = bn & 7;
    __shared__ float tile[64][65];
    const float* vb = v + ((size_t)b * L_SEQ) * DINNER + n * HEADDIM_;
#pragma unroll
    for (int i = 0; i < 16; ++i) {
        int f = i * 256 + threadIdx.x;
        int hh = f & 63, ll = f >> 6;
        tile[hh][ll] = vb[(size_t)(l0 + ll) * DINNER + (h0 + hh)];
    }
    __syncthreads();
    short* vrow = vt + ((size_t)bn * HEADDIM_) * L_SEQ;
#pragma unroll
    for (int i = 0; i < 16; ++i) {
        int f = i * 256 + threadIdx.x;
        int ll = f & 63, hh = f >> 6;
        vrow[(size_t)(h0 + hh) * L_SEQ + (l0 + ll)] = f2bf(tile[hh][ll]);
    }
}

// Stage 2: fused score-gen + MFMA matmul.
// Block = 4 waves. Each wave owns the SAME 16-row t-tile but a distinct
// 128-wide l-range (split-K in registers); LDS reduction at the end.
// A-fragment (scores) is computed directly in the lane that owns it:
//   A[m=lane&15][k=quad*8+j]  ->  lane computes S[t_base+(lane&15)][l0+quad*8+j]
__global__ __launch_bounds__(256, 2) void vand_main(const float* __restrict__ v,
                                                    const float* __restrict__ q,
                                                    const float* __restrict__ k,
                                                    const short* __restrict__ vt,
                                                    float* __restrict__ out) {
    const int tid  = threadIdx.x;
    const int w    = tid >> 6;        // wave 0..3 -> l-range
    const int lane = tid & 63;
    const int tl   = lane & 15;
    const int quad = lane >> 4;
    const int ttile = blockIdx.x;     // 0..31
    const int bn    = blockIdx.y;     // 0..15
    const int b = bn >> 3, n = bn & 7;

    const int   t  = ttile * 16 + tl;
    const float tf = (float)t;
    const float et = EPS_F * tf;      // k-part: arg = (EPS*t) * k_val

    // q row for this lane's t, pre-scaled by EPS
    const float* qrow = q + ((size_t)(b * L_SEQ + t)) * (NHEADS_ * QKD) + n * QKD;
    float qs[QKD];
#pragma unroll
    for (int d4 = 0; d4 < 4; ++d4) {
        float4 tq = *(const float4*)(qrow + d4 * 4);
        qs[d4 * 4 + 0] = EPS_F * tq.x;
        qs[d4 * 4 + 1] = EPS_F * tq.y;
        qs[d4 * 4 + 2] = EPS_F * tq.z;
        qs[d4 * 4 + 3] = EPS_F * tq.w;
    }

    const float* kbase = k + ((size_t)b * L_SEQ) * (NHEADS_ * QKD) + n * QKD;
    const short* vrow  = vt + ((size_t)bn * HEADDIM_) * L_SEQ;

    floatx4 acc[8] = {};   // 8 h-tiles of 16, accumulator C-layout

#pragma unroll
    for (int c = 0; c < 4; ++c) {
        const int   lq  = w * 128 + c * 32 + quad * 8;  // lane's first l of this chunk
        const float flq = (float)lq;
        short8 af;
#pragma unroll
        for (int j = 0; j < 8; ++j) {
            const float  lf   = flq + (float)j;
            const float* krow = kbase + (size_t)(lq + j) * (NHEADS_ * QKD);
            float s = 0.f;
#pragma unroll
            for (int d4 = 0; d4 < 4; ++d4) {
                float4 kq = *(const float4*)(krow + d4 * 4);
                s += cosrev(qs[d4 * 4 + 0] * lf) - cosrev(et * kq.x);
                s += cosrev(qs[d4 * 4 + 1] * lf) - cosrev(et * kq.y);
                s += cosrev(qs[d4 * 4 + 2] * lf) - cosrev(et * kq.z);
                s += cosrev(qs[d4 * 4 + 3] * lf) - cosrev(et * kq.w);
            }
            af[j] = f2bf(s);
        }
#pragma unroll
        for (int ht = 0; ht < 8; ++ht) {
            // B[k=quad*8+j][nn=tl] = V[lq+j][ht*16+tl] = VT[ht*16+tl][lq+j]
            const short8 bfr = *(const short8*)(vrow + (size_t)(ht * 16 + tl) * L_SEQ + lq);
            acc[ht] = __builtin_amdgcn_mfma_f32_16x16x32_bf16(af, bfr, acc[ht], 0, 0, 0);
        }
    }

    // Cross-wave (split-K) reduction in LDS. Pad 33 -> conflict-free scalar writes.
    __shared__ float red[4][64][33];
#pragma unroll
    for (int ht = 0; ht < 8; ++ht)
#pragma unroll
        for (int r = 0; r < 4; ++r)
            red[w][lane][ht * 4 + r] = acc[ht][r];
    __syncthreads();

    // C/D layout: lane quad*16+tl holds O[t_loc=quad*4+reg][h=ht*16+tl]
    const float* vbase = v   + ((size_t)b * L_SEQ) * DINNER + n * HEADDIM_;
    float*       obase = out + ((size_t)b * L_SEQ) * DINNER + n * HEADDIM_;
#pragma unroll
    for (int i = 0; i < 8; ++i) {
        int e    = i * 256 + tid;     // 2048 outputs per block
        int h    = e & 127;
        int tloc = e >> 7;            // 0..15
        int lidx = ((tloc >> 2) << 4) + (h & 15);   // source lane
        int aidx = ((h >> 4) << 2) + (tloc & 3);    // acc index ht*4+reg
        float sum = red[0][lidx][aidx] + red[1][lidx][aidx]
                  + red[2][lidx][aidx] + red[3][lidx][aidx];
        size_t gi = (size_t)(ttile * 16 + tloc) * DINNER + h;
        obase[gi] = vbase[gi] + STD_F * sum;
    }
}

extern "C" void kernel_launch(void* const* d_in, const int* in_sizes, int n_in,
                              void* d_out, int out_size, void* d_ws, size_t ws_size,
                              hipStream_t stream) {
    const float* v = (const float*)d_in[0];
    const float* q = (const float*)d_in[1];
    const float* k = (const float*)d_in[2];
    float* out = (float*)d_out;
    short* vt  = (short*)d_ws;   // 16*128*512 bf16 = 2 MiB

    vtrans_kernel<<<dim3(L_SEQ / 64, HEADDIM_ / 64, 16), 256, 0, stream>>>(v, vt);
    vand_main<<<dim3(L_SEQ / 16, 16), 256, 0, stream>>>(v, q, k, vt, out);
}

// Round 2
// 84.793 us; speedup vs baseline: 1.0706x; 1.0706x over previous
//
#include <hip/hip_runtime.h>

#define L_SEQ   512
#define NHEADS_ 8
#define HEADDIM_ 128
#define QKD     16
#define DINNER  1024
#define EPS_F   1e-3f
#define STD_F   0.0078125f   // 1/sqrt(2*512*16) = 1/128

typedef __attribute__((ext_vector_type(8))) short  short8;
typedef __attribute__((ext_vector_type(4))) float  floatx4;

// cos(2*pi*rev): v_cos_f32 takes revolutions; reduce to [0,1) first.
__device__ __forceinline__ float cosrev(float rev) {
    float r = rev - floorf(rev);
    return __builtin_amdgcn_cosf(r);
}

// float -> bf16 bits, round-to-nearest-even
__device__ __forceinline__ unsigned short f2bf_rne(float x) {
    union { float f; unsigned int u; } v;
    v.f = x;
    unsigned int r = v.u + 0x7fffu + ((v.u >> 16) & 1u);
    return (unsigned short)(r >> 16);
}
// cheap round-half-up (max err identical to RNE; no tie-to-even)
__device__ __forceinline__ unsigned short f2bf_fast(float x) {
    union { float f; unsigned int u; } v;
    v.f = x;
    return (unsigned short)((v.u + 0x8000u) >> 16);
}

// Prep kernel, two jobs split by blockIdx.x:
//  blocks [0,512):  ks[bn][t][l] = sum_d cos(2pi*EPS*k[b,l,n,d]*t)  (fp32)
//                   Chebyshev recurrence along t (32-step chunks), lanes own l.
//  blocks [512,768): vt[bn][h][l] = bf16(v[b,l,n*128+h])  (64x64 LDS transpose)
__global__ __launch_bounds__(256) void prep_kernel(const float* __restrict__ v,
                                                   const float* __restrict__ k,
                                                   unsigned short* __restrict__ vt,
                                                   float* __restrict__ ks) {
    const int bid = blockIdx.x;
    const int tid = threadIdx.x;
    if (bid < 512) {
        const int bn = bid & 15, tc = (bid >> 4) & 15, lh = bid >> 8;
        const int b = bn >> 3, n = bn & 7;
        const int l = lh * 256 + tid;
        const float t0f = (float)(tc * 32);
        const float* krow = k + ((size_t)(b * L_SEQ + l)) * (NHEADS_ * QKD) + n * QKD;
        float M[16], C1[16], C0[16];   // C1 = cos at current t, C0 = at t-1
#pragma unroll
        for (int d4 = 0; d4 < 4; ++d4) {
            float4 kk = *(const float4*)(krow + 4 * d4);
            float dl[4] = {EPS_F * kk.x, EPS_F * kk.y, EPS_F * kk.z, EPS_F * kk.w};
#pragma unroll
            for (int e = 0; e < 4; ++e) {
                int d = d4 * 4 + e;
                M[d]  = 2.f * cosrev(dl[e]);
                C1[d] = cosrev(dl[e] * t0f);
                C0[d] = cosrev(dl[e] * (t0f - 1.f));
            }
        }
        float* kout = ks + ((size_t)bn * L_SEQ) * L_SEQ + (size_t)(tc * 32) * L_SEQ + l;
#pragma unroll
        for (int m = 0; m < 32; ++m) {
            float s0 = (C1[0] + C1[1]) + (C1[2] + C1[3]);
            float s1 = (C1[4] + C1[5]) + (C1[6] + C1[7]);
            float s2 = (C1[8] + C1[9]) + (C1[10] + C1[11]);
            float s3 = (C1[12] + C1[13]) + (C1[14] + C1[15]);
            kout[(size_t)m * L_SEQ] = (s0 + s1) + (s2 + s3);
#pragma unroll
            for (int d = 0; d < 16; ++d) {
                float nx = fmaf(M[d], C1[d], -C0[d]);
                C0[d] = C1[d];
                C1[d] = nx;
            }
        }
    } else {
        const int bid2 = bid - 512;
        const int l0 = (bid2 & 7) * 64;
        const int h0 = ((bid2 >> 3) & 1) * 64;
        const int bn = bid2 >> 4;
        const int b = bn >> 3, n = bn & 7;
        __shared__ float tile[64][65];
        const float* vb = v + ((size_t)b * L_SEQ) * DINNER + n * HEADDIM_;
#pragma unroll
        for (int i = 0; i < 16; ++i) {
            int f = i * 256 + tid;
            int hh = f & 63, ll = f >> 6;
            tile[hh][ll] = vb[(size_t)(l0 + ll) * DINNER + (h0 + hh)];
        }
        __syncthreads();
        unsigned short* vrow = vt + ((size_t)bn * HEADDIM_) * L_SEQ;
#pragma unroll
        for (int i = 0; i < 16; ++i) {
            int f = i * 256 + tid;
            int ll = f & 63, hh = f >> 6;
            vrow[(size_t)(h0 + hh) * L_SEQ + (l0 + ll)] = f2bf_rne(tile[hh][ll]);
        }
    }
}

// Main kernel: fused Q-part Chebyshev score-gen + ks subtract + MFMA matmul.
// l-permutation: MFMA chunk c, lane (w,quad,jj) <-> l = w*128 + quad*32 + c*8 + jj,
// so each lane owns 32 CONSECUTIVE l values -> one recurrence chain per d.
__global__ __launch_bounds__(256, 2) void vand_main(const float* __restrict__ v,
                                                    const float* __restrict__ q,
                                                    const unsigned short* __restrict__ vt,
                                                    const float* __restrict__ ks,
                                                    float* __restrict__ out) {
    const int tid  = threadIdx.x;
    const int w    = tid >> 6;
    const int lane = tid & 63;
    const int tl   = lane & 15;
    const int quad = lane >> 4;
    const int ttile = blockIdx.x;     // 0..31
    const int bn    = blockIdx.y;     // 0..15
    const int b = bn >> 3, n = bn & 7;

    const int   t   = ttile * 16 + tl;
    const int   l0  = w * 128 + quad * 32;
    const float l0f = (float)l0;

    const float* qrow = q + ((size_t)(b * L_SEQ + t)) * (NHEADS_ * QKD) + n * QKD;
    float M[16], C1[16], C0[16];
#pragma unroll
    for (int d4 = 0; d4 < 4; ++d4) {
        float4 qq = *(const float4*)(qrow + 4 * d4);
        float dl[4] = {EPS_F * qq.x, EPS_F * qq.y, EPS_F * qq.z, EPS_F * qq.w};
#pragma unroll
        for (int e = 0; e < 4; ++e) {
            int d = d4 * 4 + e;
            M[d]  = 2.f * cosrev(dl[e]);
            C1[d] = cosrev(dl[e] * l0f);
            C0[d] = cosrev(dl[e] * (l0f - 1.f));
        }
    }

    const unsigned short* vrow  = vt + ((size_t)bn * HEADDIM_) * L_SEQ;
    const float*          ksrow = ks + ((size_t)(bn * L_SEQ + t)) * L_SEQ + l0;

    floatx4 acc[8] = {};   // 8 h-tiles of 16

#pragma unroll
    for (int c = 0; c < 4; ++c) {
        float4 kv0 = *(const float4*)(ksrow + c * 8);
        float4 kv1 = *(const float4*)(ksrow + c * 8 + 4);
        const float kvv[8] = {kv0.x, kv0.y, kv0.z, kv0.w, kv1.x, kv1.y, kv1.z, kv1.w};
        short8 af;
#pragma unroll
        for (int jj = 0; jj < 8; ++jj) {
            float s0 = (C1[0] + C1[1]) + (C1[2] + C1[3]);
            float s1 = (C1[4] + C1[5]) + (C1[6] + C1[7]);
            float s2 = (C1[8] + C1[9]) + (C1[10] + C1[11]);
            float s3 = (C1[12] + C1[13]) + (C1[14] + C1[15]);
            float s  = ((s0 + s1) + (s2 + s3)) - kvv[jj];
            af[jj] = (short)f2bf_fast(s);
#pragma unroll
            for (int d = 0; d < 16; ++d) {
                float nx = fmaf(M[d], C1[d], -C0[d]);
                C0[d] = C1[d];
                C1[d] = nx;
            }
        }
#pragma unroll
        for (int ht = 0; ht < 8; ++ht) {
            const short8 bfr = *(const short8*)((const short*)vrow +
                                  (size_t)(ht * 16 + tl) * L_SEQ + l0 + c * 8);
            acc[ht] = __builtin_amdgcn_mfma_f32_16x16x32_bf16(af, bfr, acc[ht], 0, 0, 0);
        }
    }

    // Cross-wave (split-K) reduction in LDS. Pad 33 -> conflict-free scalar writes.
    __shared__ float red[4][64][33];
#pragma unroll
    for (int ht = 0; ht < 8; ++ht)
#pragma unroll
        for (int r = 0; r < 4; ++r)
            red[w][lane][ht * 4 + r] = acc[ht][r];
    __syncthreads();

    // C/D layout: lane quad*16+tl holds O[t_loc=quad*4+reg][h=ht*16+tl]
    const float* vbase = v   + ((size_t)b * L_SEQ) * DINNER + n * HEADDIM_;
    float*       obase = out + ((size_t)b * L_SEQ) * DINNER + n * HEADDIM_;
#pragma unroll
    for (int i = 0; i < 8; ++i) {
        int e    = i * 256 + tid;     // 2048 outputs per block
        int h    = e & 127;
        int tloc = e >> 7;            // 0..15
        int lidx = ((tloc >> 2) << 4) + (h & 15);   // source lane
        int aidx = ((h >> 4) << 2) + (tloc & 3);    // acc index ht*4+reg
        float sum = red[0][lidx][aidx] + red[1][lidx][aidx]
                  + red[2][lidx][aidx] + red[3][lidx][aidx];
        size_t gi = (size_t)(ttile * 16 + tloc) * DINNER + h;
        obase[gi] = vbase[gi] + STD_F * sum;
    }
}

extern "C" void kernel_launch(void* const* d_in, const int* in_sizes, int n_in,
                              void* d_out, int out_size, void* d_ws, size_t ws_size,
                              hipStream_t stream) {
    const float* v = (const float*)d_in[0];
    const float* q = (const float*)d_in[1];
    const float* k = (const float*)d_in[2];
    float* out = (float*)d_out;
    unsigned short* vt = (unsigned short*)d_ws;              // 16*128*512 bf16 = 2 MiB
    float* ks = (float*)((char*)d_ws + (2u << 20));          // 16*512*512 fp32 = 16.8 MiB

    prep_kernel<<<dim3(768), 256, 0, stream>>>(v, k, vt, ks);
    vand_main<<<dim3(L_SEQ / 16, 16), 256, 0, stream>>>(v, q, vt, ks, out);
}

// Round 3
// 77.306 us; speedup vs baseline: 1.1743x; 1.0969x over previous
//
#include <hip/hip_runtime.h>

#define L_SEQ   512
#define NHEADS_ 8
#define HEADDIM_ 128
#define QKD     16
#define DINNER  1024
#define EPS_F   1e-3f
#define STD_F   0.0078125f   // 1/sqrt(2*512*16) = 1/128

// LDS layout for KS[t_local][l]: addr = t*KS_ROW + (l>>5)*33 + (l&31)
// KS_ROW=529 (odd, 529%32=17) spreads t across banks; chunk stride 33 spreads
// the 16 l-chunks. Phase-A stores: banks (chunk+off)%32, 2-way max (free).
// Phase-B reads (lane quad,tl): bank=(17*tl + 33*(4w+quad) + 8c + jj)%32, ~2-way.
#define KS_ROW  529

typedef __attribute__((ext_vector_type(8))) short  short8;
typedef __attribute__((ext_vector_type(4))) float  floatx4;
typedef __attribute__((ext_vector_type(2))) float  float2v;

// cos(2*pi*rev): v_cos_f32 takes revolutions; reduce to [0,1) first.
__device__ __forceinline__ float cosrev(float rev) {
    float r = rev - floorf(rev);
    return __builtin_amdgcn_cosf(r);
}

// float -> bf16 bits, round-to-nearest-even
__device__ __forceinline__ unsigned short f2bf_rne(float x) {
    union { float f; unsigned int u; } v;
    v.f = x;
    unsigned int r = v.u + 0x7fffu + ((v.u >> 16) & 1u);
    return (unsigned short)(r >> 16);
}
// cheap round-half-up
__device__ __forceinline__ unsigned short f2bf_fast(float x) {
    union { float f; unsigned int u; } v;
    v.f = x;
    return (unsigned short)((v.u + 0x8000u) >> 16);
}

// Kernel 1: vt[bn][h][l] = bf16(v[b, l, n*128+h])  -- 64x64 LDS transpose, 256 blocks
__global__ __launch_bounds__(256) void vtrans_kernel(const float* __restrict__ v,
                                                     unsigned short* __restrict__ vt) {
    const int bid = blockIdx.x;
    const int tid = threadIdx.x;
    const int l0 = (bid & 7) * 64;
    const int h0 = ((bid >> 3) & 1) * 64;
    const int bn = bid >> 4;
    const int b = bn >> 3, n = bn & 7;
    __shared__ float tile[64][65];
    const float* vb = v + ((size_t)b * L_SEQ) * DINNER + n * HEADDIM_;
#pragma unroll
    for (int i = 0; i < 16; ++i) {
        int f = i * 256 + tid;
        int hh = f & 63, ll = f >> 6;
        tile[hh][ll] = vb[(size_t)(l0 + ll) * DINNER + (h0 + hh)];
    }
    __syncthreads();
    unsigned short* vrow = vt + ((size_t)bn * HEADDIM_) * L_SEQ;
#pragma unroll
    for (int i = 0; i < 16; ++i) {
        int f = i * 256 + tid;
        int ll = f & 63, hh = f >> 6;
        vrow[(size_t)(h0 + hh) * L_SEQ + (l0 + ll)] = f2bf_rne(tile[hh][ll]);
    }
}

// Kernel 2: fused k-part Chebyshev (phase A -> LDS) + q-part Chebyshev + MFMA.
// Block = 4 waves, 16 t-rows (ttile), one (b,n). Split-K over l across waves.
// l-permutation: chunk c, lane (w,quad), slot jj  <->  l = w*128 + quad*32 + c*8 + jj.
__global__ __launch_bounds__(256, 2) void vand_fused(const float* __restrict__ v,
                                                     const float* __restrict__ q,
                                                     const float* __restrict__ k,
                                                     const unsigned short* __restrict__ vt,
                                                     float* __restrict__ out) {
    const int tid  = threadIdx.x;
    const int w    = tid >> 6;
    const int lane = tid & 63;
    const int tl   = lane & 15;
    const int quad = lane >> 4;
    const int ttile = blockIdx.x;     // 0..31
    const int bn    = blockIdx.y;     // 0..15
    const int b = bn >> 3, n = bn & 7;
    const float t0f = (float)(ttile * 16);

    __shared__ float ksl[16 * KS_ROW];          // 33.9 KB
    __shared__ float red[4][64][33];            // 33.8 KB

    // ---- Phase A: KS[t][l] = sum_d cos(2pi*EPS*k[b,l,n,d]*t), t in this tile ----
#pragma unroll
    for (int rep = 0; rep < 2; ++rep) {
        const int l = tid + rep * 256;
        const float* krow = k + ((size_t)(b * L_SEQ + l)) * (NHEADS_ * QKD) + n * QKD;
        float kk[16];
#pragma unroll
        for (int d4 = 0; d4 < 4; ++d4) {
            float4 t4 = *(const float4*)(krow + 4 * d4);
            kk[d4 * 4 + 0] = t4.x; kk[d4 * 4 + 1] = t4.y;
            kk[d4 * 4 + 2] = t4.z; kk[d4 * 4 + 3] = t4.w;
        }
        float2v M2[8], C1[8], C0[8];
#pragma unroll
        for (int i = 0; i < 8; ++i) {
            float a0 = EPS_F * kk[2 * i], a1 = EPS_F * kk[2 * i + 1];
            M2[i].x = 2.f * cosrev(a0);          M2[i].y = 2.f * cosrev(a1);
            C1[i].x = cosrev(a0 * t0f);          C1[i].y = cosrev(a1 * t0f);
            C0[i].x = cosrev(a0 * (t0f - 1.f));  C0[i].y = cosrev(a1 * (t0f - 1.f));
        }
        const int base = (l >> 5) * 33 + (l & 31);
#pragma unroll
        for (int m = 0; m < 16; ++m) {
            float2v s = ((C1[0] + C1[1]) + (C1[2] + C1[3]))
                      + ((C1[4] + C1[5]) + (C1[6] + C1[7]));
            ksl[m * KS_ROW + base] = s.x + s.y;
#pragma unroll
            for (int i = 0; i < 8; ++i) {
                float2v nx = M2[i] * C1[i] - C0[i];
                C0[i] = C1[i];
                C1[i] = nx;
            }
        }
    }
    __syncthreads();

    // ---- Phase B: q-part recurrence + subtract KS + MFMA ----
    const int   t   = ttile * 16 + tl;
    const int   l0  = w * 128 + quad * 32;
    const float l0f = (float)l0;

    const float* qrow = q + ((size_t)(b * L_SEQ + t)) * (NHEADS_ * QKD) + n * QKD;
    float2v M2[8], C1[8], C0[8];
#pragma unroll
    for (int d4 = 0; d4 < 4; ++d4) {
        float4 qq = *(const float4*)(qrow + 4 * d4);
        float aa[4] = {EPS_F * qq.x, EPS_F * qq.y, EPS_F * qq.z, EPS_F * qq.w};
#pragma unroll
        for (int e = 0; e < 2; ++e) {
            int i = d4 * 2 + e;
            float a0 = aa[2 * e], a1 = aa[2 * e + 1];
            M2[i].x = 2.f * cosrev(a0);          M2[i].y = 2.f * cosrev(a1);
            C1[i].x = cosrev(a0 * l0f);          C1[i].y = cosrev(a1 * l0f);
            C0[i].x = cosrev(a0 * (l0f - 1.f));  C0[i].y = cosrev(a1 * (l0f - 1.f));
        }
    }

    const unsigned short* vrow = vt + ((size_t)bn * HEADDIM_) * L_SEQ;
    const int klds = tl * KS_ROW + (4 * w + quad) * 33;

    floatx4 acc[8] = {};

#pragma unroll
    for (int c = 0; c < 4; ++c) {
        float kv[8];
#pragma unroll
        for (int jj = 0; jj < 8; ++jj) kv[jj] = ksl[klds + c * 8 + jj];
        short8 af;
#pragma unroll
        for (int jj = 0; jj < 8; ++jj) {
            float2v sv = ((C1[0] + C1[1]) + (C1[2] + C1[3]))
                       + ((C1[4] + C1[5]) + (C1[6] + C1[7]));
            float s = (sv.x + sv.y) - kv[jj];
            af[jj] = (short)f2bf_fast(s);
#pragma unroll
            for (int i = 0; i < 8; ++i) {
                float2v nx = M2[i] * C1[i] - C0[i];
                C0[i] = C1[i];
                C1[i] = nx;
            }
        }
#pragma unroll
        for (int ht = 0; ht < 8; ++ht) {
            const short8 bfr = *(const short8*)((const short*)vrow +
                                  (size_t)(ht * 16 + tl) * L_SEQ + l0 + c * 8);
            acc[ht] = __builtin_amdgcn_mfma_f32_16x16x32_bf16(af, bfr, acc[ht], 0, 0, 0);
        }
    }

    // ---- split-K reduction + epilogue ----
#pragma unroll
    for (int ht = 0; ht < 8; ++ht)
#pragma unroll
        for (int r = 0; r < 4; ++r)
            red[w][lane][ht * 4 + r] = acc[ht][r];
    __syncthreads();

    const float* vbase = v   + ((size_t)b * L_SEQ) * DINNER + n * HEADDIM_;
    float*       obase = out + ((size_t)b * L_SEQ) * DINNER + n * HEADDIM_;
#pragma unroll
    for (int i = 0; i < 8; ++i) {
        int e    = i * 256 + tid;     // 2048 outputs per block
        int h    = e & 127;
        int tloc = e >> 7;
        int lidx = ((tloc >> 2) << 4) + (h & 15);
        int aidx = ((h >> 4) << 2) + (tloc & 3);
        float sum = red[0][lidx][aidx] + red[1][lidx][aidx]
                  + red[2][lidx][aidx] + red[3][lidx][aidx];
        size_t gi = (size_t)(ttile * 16 + tloc) * DINNER + h;
        obase[gi] = vbase[gi] + STD_F * sum;
    }
}

extern "C" void kernel_launch(void* const* d_in, const int* in_sizes, int n_in,
                              void* d_out, int out_size, void* d_ws, size_t ws_size,
                              hipStream_t stream) {
    const float* v = (const float*)d_in[0];
    const float* q = (const float*)d_in[1];
    const float* k = (const float*)d_in[2];
    float* out = (float*)d_out;
    unsigned short* vt = (unsigned short*)d_ws;   // 16*128*512 bf16 = 2 MiB

    vtrans_kernel<<<dim3(256), 256, 0, stream>>>(v, vt);
    vand_fused<<<dim3(L_SEQ / 16, 16), 256, 0, stream>>>(v, q, k, vt, out);
}

// Round 4
// 76.792 us; speedup vs baseline: 1.1821x; 1.0067x over previous
//
#include <hip/hip_runtime.h>

#define L_SEQ   512
#define NHEADS_ 8
#define HEADDIM_ 128
#define QKD     16
#define DINNER  1024
#define EPS_F   1e-3f
#define STD_F   0.0078125f   // 1/sqrt(2*512*16) = 1/128

// LDS layout for KS[t_local][l]: addr = t*KS_ROW + (l>>5)*33 + (l&31)
// KS_ROW=529 (529%32=17); phase-A stores and phase-B reads both <=2-way (free).
#define KS_ROW  529

typedef __attribute__((ext_vector_type(8))) short  short8;
typedef __attribute__((ext_vector_type(4))) float  floatx4;
typedef __attribute__((ext_vector_type(2))) float  float2v;

// cos(2*pi*rev): v_cos_f32 takes revolutions; reduce to [0,1) first.
__device__ __forceinline__ float cosrev(float rev) {
    float r = rev - floorf(rev);
    return __builtin_amdgcn_cosf(r);
}

// 2*cos(2*pi*a) for tiny |a| (<= ~0.008 rev): even poly, err ~2e-12.
__device__ __forceinline__ float two_cos_small(float a) {
    float x = a * a;
    return fmaf(fmaf(x, 129.8787876f, -39.4784176f), x, 2.0f);
}

// float -> bf16 bits, round-to-nearest-even
__device__ __forceinline__ unsigned short f2bf_rne(float x) {
    union { float f; unsigned int u; } v;
    v.f = x;
    unsigned int r = v.u + 0x7fffu + ((v.u >> 16) & 1u);
    return (unsigned short)(r >> 16);
}
// cheap round-half-up
__device__ __forceinline__ unsigned short f2bf_fast(float x) {
    union { float f; unsigned int u; } v;
    v.f = x;
    return (unsigned short)((v.u + 0x8000u) >> 16);
}

// Kernel 1: vt[bn][h][l] = bf16(v[b, l, n*128+h])  -- 64x64 LDS transpose, 256 blocks
__global__ __launch_bounds__(256) void vtrans_kernel(const float* __restrict__ v,
                                                     unsigned short* __restrict__ vt) {
    const int bid = blockIdx.x;
    const int tid = threadIdx.x;
    const int l0 = (bid & 7) * 64;
    const int h0 = ((bid >> 3) & 1) * 64;
    const int bn = bid >> 4;
    const int b = bn >> 3, n = bn & 7;
    __shared__ float tile[64][65];
    const float* vb = v + ((size_t)b * L_SEQ) * DINNER + n * HEADDIM_;
#pragma unroll
    for (int i = 0; i < 16; ++i) {
        int f = i * 256 + tid;
        int hh = f & 63, ll = f >> 6;
        tile[hh][ll] = vb[(size_t)(l0 + ll) * DINNER + (h0 + hh)];
    }
    __syncthreads();
    unsigned short* vrow = vt + ((size_t)bn * HEADDIM_) * L_SEQ;
#pragma unroll
    for (int i = 0; i < 16; ++i) {
        int f = i * 256 + tid;
        int ll = f & 63, hh = f >> 6;
        vrow[(size_t)(h0 + hh) * L_SEQ + (l0 + ll)] = f2bf_rne(tile[hh][ll]);
    }
}

// Kernel 2: fused k-part Chebyshev (phase A -> LDS, PER-WAVE l-range, no barrier)
// + q-part Chebyshev + MFMA. Block = 4 waves, 16 t-rows, one (b,n).
// l-permutation: chunk c, lane (w,quad), slot jj <-> l = w*128 + quad*32 + c*8 + jj.
__global__ __launch_bounds__(256, 2) void vand_fused(const float* __restrict__ v,
                                                     const float* __restrict__ q,
                                                     const float* __restrict__ k,
                                                     const unsigned short* __restrict__ vt,
                                                     float* __restrict__ out) {
    const int tid  = threadIdx.x;
    const int w    = tid >> 6;
    const int lane = tid & 63;
    const int tl   = lane & 15;
    const int quad = lane >> 4;
    const int ttile = blockIdx.x;     // 0..31
    const int bn    = blockIdx.y;     // 0..15
    const int b = bn >> 3, n = bn & 7;
    const float t0f = (float)(ttile * 16);

    __shared__ float ksl[16 * KS_ROW];          // 33.9 KB
    __shared__ float red[4][64][33];            // 33.8 KB

    // ---- Phase A: KS[t][l] for t in tile, l in THIS WAVE's 128-range ----
    // Wave w writes l in [w*128, w*128+128) and reads back only that range in
    // phase B -> same-wave ds ordering suffices, NO __syncthreads needed.
#pragma unroll
    for (int rep = 0; rep < 2; ++rep) {
        const int l = w * 128 + rep * 64 + lane;
        const float* krow = k + ((size_t)(b * L_SEQ + l)) * (NHEADS_ * QKD) + n * QKD;
        float kk[16];
#pragma unroll
        for (int d4 = 0; d4 < 4; ++d4) {
            float4 t4 = *(const float4*)(krow + 4 * d4);
            kk[d4 * 4 + 0] = t4.x; kk[d4 * 4 + 1] = t4.y;
            kk[d4 * 4 + 2] = t4.z; kk[d4 * 4 + 3] = t4.w;
        }
        float2v M2[8], C1[8], C0[8];
#pragma unroll
        for (int i = 0; i < 8; ++i) {
            float a0 = EPS_F * kk[2 * i], a1 = EPS_F * kk[2 * i + 1];
            M2[i].x = two_cos_small(a0);         M2[i].y = two_cos_small(a1);
            C1[i].x = cosrev(a0 * t0f);          C1[i].y = cosrev(a1 * t0f);
            C0[i].x = cosrev(a0 * (t0f - 1.f));  C0[i].y = cosrev(a1 * (t0f - 1.f));
        }
        const int base = (l >> 5) * 33 + (l & 31);
#pragma unroll
        for (int m = 0; m < 16; ++m) {
            float2v s = ((C1[0] + C1[1]) + (C1[2] + C1[3]))
                      + ((C1[4] + C1[5]) + (C1[6] + C1[7]));
            ksl[m * KS_ROW + base] = s.x + s.y;
#pragma unroll
            for (int i = 0; i < 8; ++i) {
                float2v nx = M2[i] * C1[i] - C0[i];
                C0[i] = C1[i];
                C1[i] = nx;
            }
        }
    }

    // ---- Phase B: q-part recurrence + subtract KS + MFMA ----
    const int   t   = ttile * 16 + tl;
    const int   l0  = w * 128 + quad * 32;
    const float l0f = (float)l0;

    const float* qrow = q + ((size_t)(b * L_SEQ + t)) * (NHEADS_ * QKD) + n * QKD;
    float2v M2[8], C1[8], C0[8];
#pragma unroll
    for (int d4 = 0; d4 < 4; ++d4) {
        float4 qq = *(const float4*)(qrow + 4 * d4);
        float aa[4] = {EPS_F * qq.x, EPS_F * qq.y, EPS_F * qq.z, EPS_F * qq.w};
#pragma unroll
        for (int e = 0; e < 2; ++e) {
            int i = d4 * 2 + e;
            float a0 = aa[2 * e], a1 = aa[2 * e + 1];
            M2[i].x = two_cos_small(a0);         M2[i].y = two_cos_small(a1);
            C1[i].x = cosrev(a0 * l0f);          C1[i].y = cosrev(a1 * l0f);
            C0[i].x = cosrev(a0 * (l0f - 1.f));  C0[i].y = cosrev(a1 * (l0f - 1.f));
        }
    }

    const unsigned short* vrow = vt + ((size_t)bn * HEADDIM_) * L_SEQ;
    const int klds = tl * KS_ROW + (4 * w + quad) * 33;

    floatx4 acc[8] = {};

#pragma unroll
    for (int c = 0; c < 4; ++c) {
        float kv[8];
#pragma unroll
        for (int jj = 0; jj < 8; ++jj) kv[jj] = ksl[klds + c * 8 + jj];
        short8 af;
#pragma unroll
        for (int jj = 0; jj < 8; ++jj) {
            float2v sv = ((C1[0] + C1[1]) + (C1[2] + C1[3]))
                       + ((C1[4] + C1[5]) + (C1[6] + C1[7]));
            float s = (sv.x + sv.y) - kv[jj];
            af[jj] = (short)f2bf_fast(s);
#pragma unroll
            for (int i = 0; i < 8; ++i) {
                float2v nx = M2[i] * C1[i] - C0[i];
                C0[i] = C1[i];
                C1[i] = nx;
            }
        }
#pragma unroll
        for (int ht = 0; ht < 8; ++ht) {
            const short8 bfr = *(const short8*)((const short*)vrow +
                                  (size_t)(ht * 16 + tl) * L_SEQ + l0 + c * 8);
            acc[ht] = __builtin_amdgcn_mfma_f32_16x16x32_bf16(af, bfr, acc[ht], 0, 0, 0);
        }
    }

    // ---- split-K reduction + epilogue ----
#pragma unroll
    for (int ht = 0; ht < 8; ++ht)
#pragma unroll
        for (int r = 0; r < 4; ++r)
            red[w][lane][ht * 4 + r] = acc[ht][r];
    __syncthreads();

    const float* vbase = v   + ((size_t)b * L_SEQ) * DINNER + n * HEADDIM_;
    float*       obase = out + ((size_t)b * L_SEQ) * DINNER + n * HEADDIM_;
#pragma unroll
    for (int i = 0; i < 2; ++i) {
        int g    = i * 256 + tid;      // 512 float4 groups (16 t x 32 h-quads)
        int hb   = g & 31;             // h = hb*4 + e
        int tloc = g >> 5;             // 0..15
        int lidx0 = ((tloc >> 2) << 4) + ((hb & 3) << 2);
        int aidx  = ((hb >> 2) << 2) + (tloc & 3);
        float4 sum;
        float* sp = &sum.x;
#pragma unroll
        for (int e = 0; e < 4; ++e) {
            int lidx = lidx0 + e;
            sp[e] = (red[0][lidx][aidx] + red[1][lidx][aidx])
                  + (red[2][lidx][aidx] + red[3][lidx][aidx]);
        }
        size_t gi = (size_t)(ttile * 16 + tloc) * DINNER + hb * 4;
        float4 vres = *(const float4*)(vbase + gi);
        float4 o;
        o.x = fmaf(STD_F, sum.x, vres.x);
        o.y = fmaf(STD_F, sum.y, vres.y);
        o.z = fmaf(STD_F, sum.z, vres.z);
        o.w = fmaf(STD_F, sum.w, vres.w);
        *(float4*)(obase + gi) = o;
    }
}

extern "C" void kernel_launch(void* const* d_in, const int* in_sizes, int n_in,
                              void* d_out, int out_size, void* d_ws, size_t ws_size,
                              hipStream_t stream) {
    const float* v = (const float*)d_in[0];
    const float* q = (const float*)d_in[1];
    const float* k = (const float*)d_in[2];
    float* out = (float*)d_out;
    unsigned short* vt = (unsigned short*)d_ws;   // 16*128*512 bf16 = 2 MiB

    vtrans_kernel<<<dim3(256), 256, 0, stream>>>(v, vt);
    vand_fused<<<dim3(L_SEQ / 16, 16), 256, 0, stream>>>(v, q, k, vt, out);
}